// Round 1
// baseline (338.460 us; speedup 1.0000x reference)
//
#include <hip/hip_runtime.h>
#include <math.h>

#define NB 32
#define CB 64
#define HH 224
#define WW 224
#define PADP 2
#define HP (HH + 2*PADP)   // 228
#define WP (WW + 2*PADP)   // 228
#define HW (HH*WW)         // 50176
#define HWP (HP*WP)        // 51984
#define EPSV 1e-5f

__device__ __forceinline__ float sigmoidf_(float v) { return 1.0f / (1.0f + expf(-v)); }

// Kernel 1: per-(n,c) weighted reduction over original HxW grid.
// weight(h) = 1 + [h in {1,2,H-3,H-2}]  (reflection pad multiplicity), same for w.
// pooled = mean over padded grid of x[c]*sigmoid(x[c-1]); cmean = mean of x[c].
__global__ __launch_bounds__(256) void k_pool(const float* __restrict__ x,
                                              float* __restrict__ pooled,
                                              float* __restrict__ cmean) {
    int bc = blockIdx.x;            // n*CB + c
    int c  = bc & (CB - 1);
    int cm1 = (c + CB - 1) & (CB - 1);
    const float* xs = x + (size_t)bc * HW;
    const float* xg = x + (size_t)(bc - c + cm1) * HW;
    int tid = threadIdx.x;

    float sG = 0.f, sX = 0.f;
    // HW = 50176 = 1024*49 exactly; W=224 divisible by 4 so each float4 stays in one row.
    for (int i = tid * 4; i < HW; i += 256 * 4) {
        float4 a = *(const float4*)(xs + i);
        float4 g = *(const float4*)(xg + i);
        int h  = i / WW;
        int w0 = i - h * WW;
        float wh = 1.0f + (float)((h == 1) | (h == 2) | (h == HH-3) | (h == HH-2));
        float w_0 = wh * (1.0f + (float)((w0   == 1) | (w0   == 2) | (w0   == WW-3) | (w0   == WW-2)));
        float w_1 = wh * (1.0f + (float)((w0+1 == 1) | (w0+1 == 2) | (w0+1 == WW-3) | (w0+1 == WW-2)));
        float w_2 = wh * (1.0f + (float)((w0+2 == 1) | (w0+2 == 2) | (w0+2 == WW-3) | (w0+2 == WW-2)));
        float w_3 = wh * (1.0f + (float)((w0+3 == 1) | (w0+3 == 2) | (w0+3 == WW-3) | (w0+3 == WW-2)));
        sG += w_0 * a.x * sigmoidf_(g.x);
        sG += w_1 * a.y * sigmoidf_(g.y);
        sG += w_2 * a.z * sigmoidf_(g.z);
        sG += w_3 * a.w * sigmoidf_(g.w);
        sX += w_0 * a.x + w_1 * a.y + w_2 * a.z + w_3 * a.w;
    }

    // wave reduce (64 lanes)
    for (int off = 32; off >= 1; off >>= 1) {
        sG += __shfl_xor(sG, off);
        sX += __shfl_xor(sX, off);
    }
    __shared__ float lds[8];
    int wave = tid >> 6, lane = tid & 63;
    if (lane == 0) { lds[wave * 2] = sG; lds[wave * 2 + 1] = sX; }
    __syncthreads();
    if (tid == 0) {
        float g  = lds[0] + lds[2] + lds[4] + lds[6];
        float xx = lds[1] + lds[3] + lds[5] + lds[7];
        pooled[bc] = g  * (1.0f / (float)HWP);
        cmean[bc]  = xx * (1.0f / (float)HWP);
    }
}

// Kernel 2: BatchNorm1d (training-mode batch stats, biased var) + sigmoid -> scale.
// One block per channel; lanes 0..31 hold the 32 batch values.
__global__ __launch_bounds__(64) void k_bn(const float* __restrict__ pooled,
                                           const float* __restrict__ bnw,
                                           const float* __restrict__ bnb,
                                           float* __restrict__ scale) {
    int c = blockIdx.x;
    int t = threadIdx.x;
    float v = 0.f;
    if (t < 32) v = pooled[t * CB + c];
    float s = v;
    for (int off = 16; off >= 1; off >>= 1) s += __shfl_xor(s, off);
    float mu = s * (1.0f / 32.0f);
    float d = v - mu;
    float q = d * d;
    for (int off = 16; off >= 1; off >>= 1) q += __shfl_xor(q, off);
    float var = q * (1.0f / 32.0f);
    if (t < 32) {
        float normed = d * rsqrtf(var + EPSV) * bnw[c] + bnb[c];
        scale[t * CB + c] = sigmoidf_(normed);
    }
}

// Kernel 3: one block per (n, padded row). Threads cover padded W; loop over
// channels keeping previous channel's value in a register (GLU roll gate), so
// each x element is read ~once (channel 63 twice).
__global__ __launch_bounds__(256) void k_out(const float* __restrict__ x,
                                             const float* __restrict__ scale,
                                             const float* __restrict__ cmean,
                                             const float* __restrict__ post_scale,
                                             float* __restrict__ out) {
    int b  = blockIdx.x;            // n*HP + hp
    int n  = b / HP;
    int hp = b - n * HP;
    int rh = hp - PADP; rh = rh < 0 ? -rh : (rh >= HH ? 2*HH - 2 - rh : rh);
    int wp = threadIdx.x;
    if (wp >= WP) return;
    int rw = wp - PADP; rw = rw < 0 ? -rw : (rw >= WW ? 2*WW - 2 - rw : rw);

    float ps = post_scale[0];
    const float* xrow = x + (size_t)n * CB * HW + (size_t)rh * WW;
    float* orow = out + (size_t)n * CB * HWP + (size_t)hp * WP;
    const float* sc_row = scale + n * CB;
    const float* cm_row = cmean + n * CB;

    float prev = xrow[(size_t)(CB - 1) * HW + rw];
    for (int cc = 0; cc < CB; ++cc) {
        float cur = xrow[(size_t)cc * HW + rw];
        float g = cur * sigmoidf_(prev);
        float v = (g * sc_row[cc] + cm_row[cc]) * ps;
        float o = 0.5f * v * (1.0f + erff(v * 0.70710678118654752f));  // exact GELU
        orow[(size_t)cc * HWP + wp] = o;
        prev = cur;
    }
}

extern "C" void kernel_launch(void* const* d_in, const int* in_sizes, int n_in,
                              void* d_out, int out_size, void* d_ws, size_t ws_size,
                              hipStream_t stream) {
    const float* x   = (const float*)d_in[0];
    const float* bnw = (const float*)d_in[1];
    const float* bnb = (const float*)d_in[2];
    const float* ps  = (const float*)d_in[3];
    float* out = (float*)d_out;

    float* pooled = (float*)d_ws;          // NB*CB floats
    float* cmean  = pooled + NB * CB;      // NB*CB floats
    float* scale  = cmean  + NB * CB;      // NB*CB floats

    k_pool<<<NB * CB, 256, 0, stream>>>(x, pooled, cmean);
    k_bn<<<CB, 64, 0, stream>>>(pooled, bnw, bnb, scale);
    k_out<<<NB * HP, 256, 0, stream>>>(x, scale, cmean, ps, out);
}